// Round 8
// baseline (973.668 us; speedup 1.0000x reference)
//
#include <hip/hip_runtime.h>
#include <hip/hip_bf16.h>

namespace {

constexpr int kB = 512, kN = 32, kHS = 512, kHS2 = 1024, kHS3 = 1536;
constexpr int kGS = 1024, kNZ = 56, kTE = 3;
constexpr int kNC = 4608;  // combined step-GEMM N: [U 1536 | V 1536 | Wh 1536]

typedef __attribute__((ext_vector_type(8))) short bf16x8;
typedef __attribute__((ext_vector_type(4))) float f32x4;

__device__ inline ushort f2bf(float f) {
    union { float f; unsigned u; } v; v.f = f;
    unsigned r = v.u + 0x7fffu + ((v.u >> 16) & 1u);
    return (ushort)(r >> 16);
}
__device__ inline float bf2f(ushort b) {
    union { unsigned u; float f; } v; v.u = ((unsigned)b) << 16;
    return v.f;
}

// ================= generic f32 -> bf16 copy =================================
__global__ __launch_bounds__(256) void copybf_kernel(const float* __restrict__ in,
    ushort* __restrict__ out, int n)
{
    int i = blockIdx.x * 256 + threadIdx.x;
    if (i < n) out[i] = f2bf(in[i]);
}

// gateMapT (2048 x 512): rows 0-1023 = gate_w^T, 1024-2047 = mapper_w^T
__global__ __launch_bounds__(256) void gatemap_kernel(const float* __restrict__ gw,
    const float* __restrict__ mw, ushort* __restrict__ out)
{
    int idx = blockIdx.x * 256 + threadIdx.x;  // < 2048*512
    int n = idx >> 9, k = idx & 511;
    float v = (n < kGS) ? gw[(size_t)k * kGS + n] : mw[(size_t)k * kGS + (n - kGS)];
    out[idx] = f2bf(v);
}

// ================= small precompute =========================================
__global__ __launch_bounds__(256) void deg_kernel(const float* __restrict__ adj,
    float* __restrict__ deg)
{
    int idx = blockIdx.x * 256 + threadIdx.x;  // < kB*kN
    int b = idx >> 5, v = idx & 31;
    const float* p = adj + (size_t)b * kN * kN + v;
    float s = 0.f;
    #pragma unroll
    for (int u = 0; u < kN; ++u) s += p[u * kN];
    deg[idx] = s;
}

__global__ void haspred_kernel(const float* __restrict__ deg, int* __restrict__ hp)
{
    int v = threadIdx.x;  // 32
    float s = 0.f;
    for (int b = 0; b < kB; ++b) s += deg[b * kN + v];
    hp[v] = (s > 0.f) ? 1 : 0;
}

// be (1024) = we + fe_b
__global__ void be_kernel(const float* __restrict__ fe_w,
    const float* __restrict__ fe_b, float* __restrict__ o)
{
    int j = blockIdx.x * 256 + threadIdx.x;  // < 1024
    o[j] = fe_w[(size_t)kHS * kHS2 + j] + fe_b[j];
}

// bewih[t,e] = sum_j be[j] * wih[t,e,j]   (e < 1536)
__global__ __launch_bounds__(256) void bewih_kernel(const float* __restrict__ be,
    const float* __restrict__ wih, float* __restrict__ o)
{
    int idx = blockIdx.x * 256 + threadIdx.x;  // < kTE*1536
    int t = idx / kHS3, e = idx % kHS3;
    const float* wr = wih + ((size_t)t * kHS3 + e) * kHS2;
    float s = 0.f;
    for (int j = 0; j < kHS2; ++j) s = fmaf(be[j], wr[j], s);
    o[idx] = s;
}

// biasRO (2048): [gate_b | 0]
__global__ void biasRO_kernel(const float* __restrict__ gb, float* __restrict__ o)
{
    int e = blockIdx.x * 256 + threadIdx.x;
    o[e] = (e < kGS) ? gb[e] : 0.f;
}

// ---------------- H init: H[m,h] = bf16(finit_w[nt[m],h] + finit_b[h]) ------
__global__ __launch_bounds__(256) void hinit_kernel(const int* __restrict__ nt,
    const float* __restrict__ finit_w, const float* __restrict__ finit_b,
    ushort* __restrict__ H)
{
    int idx = blockIdx.x * 256 + threadIdx.x;  // < MC*kHS
    int m = idx >> 9;
    int h = idx & 511;
    int t = nt[m];
    H[idx] = f2bf(finit_w[t * kHS + h] + finit_b[h]);
}

// ================= MFMA bf16 GEMM: C = A(bf16) @ B(bf16)^T (+bias) ==========
// Measured-good R4 kernel (unchanged): BM=128, BN=256, BK=32, 4 waves,
// 3-buffer LDS counted-vmcnt pipeline, setprio, XOR swizzle, XCD swizzle.
template<typename CT>
__global__ __launch_bounds__(256, 2) void gemm_bf16(const ushort* __restrict__ A,
    const ushort* __restrict__ B, CT* __restrict__ C,
    const float* __restrict__ bias, int M_, int N_, int K_, int lda)
{
    __shared__ ushort smem[3 * 12288];   // per buf: A 128x32 (4096) + B 256x32 (8192)
    const int tid = threadIdx.x;
    const int w = tid >> 6, l = tid & 63;
    const int l15 = l & 15;

    int nwg = gridDim.x * gridDim.y;
    int bid = blockIdx.y * gridDim.x + blockIdx.x;
    int swz = (nwg & 7) ? bid : ((bid & 7) * (nwg >> 3) + (bid >> 3));
    const int bx = swz % gridDim.x, by = swz / gridDim.x;
    const int mT = by * 128, nT = bx * 256;

    const int NT = K_ >> 5;

    auto stage = [&](const ushort* G, int ldg, int rowOff, int buf, int aOff,
                     int idx, int kt2) {
        int row = idx >> 2, sl = idx & 3;
        int gs = sl ^ ((row >> 1) & 3);
        const ushort* g = G + (size_t)(rowOff + row) * ldg + kt2 + gs * 8;
        __builtin_amdgcn_global_load_lds(
            (const __attribute__((address_space(1))) void*)g,
            (__attribute__((address_space(3))) void*)(smem + buf * 12288 + aOff + idx * 8),
            16, 0, 0);
    };
    auto stage_ph0 = [&](int t) {
        int buf = t % 3, kt2 = t * 32;
        stage(A, lda, mT, buf, 0, tid, kt2);
        stage(A, lda, mT, buf, 0, 256 + tid, kt2);
        stage(B, K_, nT, buf, 4096, tid, kt2);
    };
    auto stage_ph1 = [&](int t) {
        int buf = t % 3, kt2 = t * 32;
        stage(B, K_, nT, buf, 4096, 256 + tid, kt2);
        stage(B, K_, nT, buf, 4096, 512 + tid, kt2);
        stage(B, K_, nT, buf, 4096, 768 + tid, kt2);
    };

    f32x4 acc[8][4] = {};
    bf16x8 bfr[4];
    const int swd = ((l >> 4) ^ (l15 >> 1)) & 3;

    stage_ph0(0); stage_ph1(0);
    stage_ph0(1); stage_ph1(1);

    for (int t = 0; t < NT; ++t) {
        if (t + 1 < NT) asm volatile("s_waitcnt vmcnt(6)" ::: "memory");
        else            asm volatile("s_waitcnt vmcnt(0)" ::: "memory");
        __builtin_amdgcn_s_barrier();

        const ushort* Ab = smem + (t % 3) * 12288;
        const ushort* Bb = Ab + 4096;
        const bool st = (t + 2 < NT);

        bf16x8 af[4];
        #pragma unroll
        for (int i = 0; i < 4; ++i)
            af[i] = *reinterpret_cast<const bf16x8*>(
                &Ab[(i * 16 + l15) * 32 + swd * 8]);
        #pragma unroll
        for (int j = 0; j < 4; ++j)
            bfr[j] = *reinterpret_cast<const bf16x8*>(
                &Bb[(w * 64 + j * 16 + l15) * 32 + swd * 8]);
        if (st) stage_ph0(t + 2);
        asm volatile("s_waitcnt lgkmcnt(0)" ::: "memory");
        __builtin_amdgcn_sched_barrier(0);
        __builtin_amdgcn_s_setprio(1);
        #pragma unroll
        for (int i = 0; i < 4; ++i)
            #pragma unroll
            for (int j = 0; j < 4; ++j)
                acc[i][j] = __builtin_amdgcn_mfma_f32_16x16x32_bf16(
                    af[i], bfr[j], acc[i][j], 0, 0, 0);
        __builtin_amdgcn_s_setprio(0);
        __builtin_amdgcn_s_barrier();

        #pragma unroll
        for (int i = 0; i < 4; ++i)
            af[i] = *reinterpret_cast<const bf16x8*>(
                &Ab[((4 + i) * 16 + l15) * 32 + swd * 8]);
        if (st) stage_ph1(t + 2);
        asm volatile("s_waitcnt lgkmcnt(0)" ::: "memory");
        __builtin_amdgcn_sched_barrier(0);
        __builtin_amdgcn_s_setprio(1);
        #pragma unroll
        for (int i = 0; i < 4; ++i)
            #pragma unroll
            for (int j = 0; j < 4; ++j)
                acc[4 + i][j] = __builtin_amdgcn_mfma_f32_16x16x32_bf16(
                    af[i], bfr[j], acc[4 + i][j], 0, 0, 0);
        __builtin_amdgcn_s_setprio(0);
        __builtin_amdgcn_s_barrier();
    }

    const int row0 = (l >> 4) * 4;
    #pragma unroll
    for (int ni = 0; ni < 4; ++ni) {
        int col = nT + w * 64 + ni * 16 + l15;
        float bv = bias ? bias[col] : 0.f;
        #pragma unroll
        for (int mi = 0; mi < 8; ++mi) {
            #pragma unroll
            for (int q = 0; q < 4; ++q) {
                int row = mT + mi * 16 + row0 + q;
                float val = acc[mi][ni][q] + bv;
                if constexpr (sizeof(CT) == 2)
                    C[(size_t)row * N_ + col] = (CT)f2bf(val);
                else
                    C[(size_t)row * N_ + col] = (CT)val;
            }
        }
    }
}

template<typename CT>
void launch_gemm(const ushort* A, int lda, const ushort* B, CT* C,
                 const float* bias, int M_, int N_, int K_, hipStream_t stream)
{
    dim3 grid(N_ / 256, M_ / 128);
    gemm_bf16<CT><<<grid, 256, 0, stream>>>(A, B, C, bias, M_, N_, K_, lda);
}

// ---- mixer: AP[b,v,e] = sum_u adj[b,u,v] * P_U[b,u,e]   (e < 1536) ---------
// P row stride kNC; P_U = cols [0,1536). AP bf16 (M x 1536).
__global__ __launch_bounds__(256) void mixer_kernel(const float* __restrict__ adj,
    const ushort* __restrict__ P, ushort* __restrict__ AP)
{
    __shared__ float adjs[kN * kN];
    int b = blockIdx.y;
    int e = blockIdx.x * 256 + threadIdx.x;  // < 1536
    {
        const float4* src = reinterpret_cast<const float4*>(adj + (size_t)b * kN * kN);
        float4 v = src[threadIdx.x];
        *reinterpret_cast<float4*>(&adjs[threadIdx.x * 4]) = v;
    }
    __syncthreads();

    const size_t rbase = (size_t)b * kN * kNC + e;
    float acc[kN];
    #pragma unroll
    for (int v = 0; v < kN; ++v) acc[v] = 0.f;
    for (int u = 0; u < kN; ++u) {
        float pu = bf2f(P[rbase + (size_t)u * kNC]);
        #pragma unroll
        for (int v4 = 0; v4 < kN / 4; ++v4) {
            float4 a = *reinterpret_cast<const float4*>(&adjs[u * kN + v4 * 4]);
            acc[v4 * 4 + 0] = fmaf(a.x, pu, acc[v4 * 4 + 0]);
            acc[v4 * 4 + 1] = fmaf(a.y, pu, acc[v4 * 4 + 1]);
            acc[v4 * 4 + 2] = fmaf(a.z, pu, acc[v4 * 4 + 2]);
            acc[v4 * 4 + 3] = fmaf(a.w, pu, acc[v4 * 4 + 3]);
        }
    }
    const size_t obase = (size_t)b * kN * kHS3 + e;
    #pragma unroll
    for (int v = 0; v < kN; ++v) AP[obase + (size_t)v * kHS3] = f2bf(acc[v]);
}

// ---- gate: full GRU gating + has_pred select, H (bf16, M x 512) in place ---
// gx_c = AP[m,c] + deg_m*(P_V[m,c] + bewih[c]) + bih[c]
// gh_c = P_Wh[m,c] + bhh[c]       (c = h, h+512, h+1024)
__global__ __launch_bounds__(256) void gate_kernel(ushort* __restrict__ H,
    const ushort* __restrict__ AP, const ushort* __restrict__ P,
    const float* __restrict__ degc, const float* __restrict__ bewih,
    const float* __restrict__ bih, const float* __restrict__ bhh,
    const int* __restrict__ hp)
{
    int idx = blockIdx.x * 256 + threadIdx.x;  // < MC*kHS
    int m = idx >> 9;
    int h = idx & 511;
    float dm = degc[m];
    const size_t ap = (size_t)m * kHS3 + h;
    const size_t pv = (size_t)m * kNC + kHS3 + h;
    const size_t pw = (size_t)m * kNC + 2 * kHS3 + h;

    float gxr = bf2f(AP[ap])            + dm * (bf2f(P[pv])            + bewih[h])            + bih[h];
    float gxz = bf2f(AP[ap + kHS])      + dm * (bf2f(P[pv + kHS])      + bewih[h + kHS])      + bih[h + kHS];
    float gxn = bf2f(AP[ap + 2 * kHS])  + dm * (bf2f(P[pv + 2 * kHS])  + bewih[h + 2 * kHS])  + bih[h + 2 * kHS];
    float ghr = bf2f(P[pw])           + bhh[h];
    float ghz = bf2f(P[pw + kHS])     + bhh[h + kHS];
    float ghn = bf2f(P[pw + 2 * kHS]) + bhh[h + 2 * kHS];

    float r = 1.f / (1.f + __expf(-(gxr + ghr)));
    float z = 1.f / (1.f + __expf(-(gxz + ghz)));
    float n = tanhf(gxn + r * ghn);
    float hold = bf2f(H[idx]);
    float hnew = (1.f - z) * n + z * hold;
    H[idx] = hp[m & 31] ? f2bf(hnew) : f2bf(hold);
}

// ---------------- Hg[b,g] = sum_n sigmoid(G1) * G2 --------------------------
__global__ __launch_bounds__(256) void hg_kernel(const float* __restrict__ G12,
    float* __restrict__ Hg)
{
    int idx = blockIdx.x * 256 + threadIdx.x;  // < CH*kGS
    int b = idx >> 10, g = idx & 1023;
    size_t base = (size_t)b * kN * 2048 + g;
    float acc = 0.f;
    #pragma unroll 8
    for (int n = 0; n < kN; ++n) {
        float s  = G12[base + (size_t)n * 2048];
        float m2 = G12[base + (size_t)n * 2048 + kGS];
        float sig = 1.f / (1.f + __expf(-s));
        acc = fmaf(sig, m2, acc);
    }
    Hg[idx] = acc;
}

// ---------------- mu/logvar heads -------------------------------------------
__global__ __launch_bounds__(64) void fc_kernel(const float* __restrict__ Hg,
    const float* __restrict__ fc1_w, const float* __restrict__ fc1_b,
    const float* __restrict__ fc2_w, const float* __restrict__ fc2_b,
    float* __restrict__ out, int b0)
{
    __shared__ float hg[kGS];
    int bl = blockIdx.x;
    for (int i = threadIdx.x; i < kGS; i += 64) hg[i] = Hg[(size_t)bl * kGS + i];
    __syncthreads();
    int j = threadIdx.x;
    if (j < kNZ) {
        float s1 = fc1_b[j], s2 = fc2_b[j];
        for (int k = 0; k < kGS; ++k) {
            float h = hg[k];
            s1 = fmaf(h, fc1_w[k * kNZ + j], s1);
            s2 = fmaf(h, fc2_w[k * kNZ + j], s2);
        }
        int bg = b0 + bl;
        out[(size_t)bg * kNZ + j] = s1;
        out[(size_t)kB * kNZ + (size_t)bg * kNZ + j] = s2;
    }
}

}  // namespace

extern "C" void kernel_launch(void* const* d_in, const int* in_sizes, int n_in,
                              void* d_out, int out_size, void* d_ws, size_t ws_size,
                              hipStream_t stream)
{
    const int*   node_types = (const int*)  d_in[0];
    const float* adj        = (const float*)d_in[1];
    const float* finit_w    = (const float*)d_in[2];
    const float* finit_b    = (const float*)d_in[3];
    const float* fe_w       = (const float*)d_in[4];
    const float* fe_b       = (const float*)d_in[5];
    const float* grue_wih   = (const float*)d_in[6];
    const float* grue_whh   = (const float*)d_in[7];
    const float* grue_bih   = (const float*)d_in[8];
    const float* grue_bhh   = (const float*)d_in[9];
    const float* gate_w     = (const float*)d_in[10];
    const float* gate_b     = (const float*)d_in[11];
    const float* mapper_w   = (const float*)d_in[12];
    const float* fc1_w      = (const float*)d_in[13];
    const float* fc1_b      = (const float*)d_in[14];
    const float* fc2_w      = (const float*)d_in[15];
    const float* fc2_b      = (const float*)d_in[16];
    float* out = (float*)d_out;

    // ---- fixed region (float units) ----
    float* W = (float*)d_ws;
    size_t o = 0;
    float*  deg     = W + o; o += (size_t)kB * kN;
    int*    hp      = (int*)(W + o); o += 64;
    float*  be      = W + o; o += kHS2;
    float*  bewih   = W + o; o += kTE * kHS3;
    float*  biasRO  = W + o; o += 2048;
    float*  Hg      = W + o; o += (size_t)kB * kGS;
    ushort* gateMapT= (ushort*)(W + o); o += (size_t)2048 * kHS / 2;
    ushort* COMB    = (ushort*)(W + o); o += (size_t)kTE * kNC * kHS / 2;  // 3x4608x512
    const size_t fixedFloats = o;

    // per-graph floats: P 32x4608 bf16 (73728) + AP 32x1536 bf16 (12288)
    //                   + H 32x512 bf16 (4096) = 90112+16384 = 106496? -> 106496? no:
    // 73728 + 12288 + 4096 = 90112 + ... exact: 90112? 73728+12288=86016, +4096 = 90112.
    // Hmm: 32*4608/2=73728, 32*1536/2=24576? No: 32*1536 ushorts = 49152 ushorts/2 ... careful:
    // floats = ushorts/2. P: 32*4608 ush = 147456 ush -> 73728 f. AP: 32*1536=49152 ush -> 24576 f.
    // H: 32*512=16384 ush -> 8192 f. total = 106496 f.
    const size_t perGraph = 106496;
    int CH = 512;
    while (CH > 4 &&
           (fixedFloats + (size_t)CH * perGraph) * sizeof(float) > ws_size)
        CH >>= 1;

    // ---- chunk region pointers (also used as prep staging scratch) ----
    float* chunkBase = W + fixedFloats;

    // prep staging (dead after COMB GEMMs): wihB (3x1536x1024), WnB, WsB
    ushort* wihB = (ushort*)chunkBase;                          // 4718592 ush
    ushort* WnB  = wihB + (size_t)kTE * kHS3 * kHS2;            // 524288 ush
    ushort* WsB  = WnB  + (size_t)kHS * kHS2;                   // 524288 ush

    // ---- one-time precompute ----
    deg_kernel<<<kB * kN / 256, 256, 0, stream>>>(adj, deg);
    haspred_kernel<<<1, kN, 0, stream>>>(deg, hp);
    be_kernel<<<kHS2 / 256, 256, 0, stream>>>(fe_w, fe_b, be);
    bewih_kernel<<<kTE * kHS3 / 256, 256, 0, stream>>>(be, grue_wih, bewih);
    biasRO_kernel<<<2048 / 256, 256, 0, stream>>>(gate_b, biasRO);
    gatemap_kernel<<<2048 * kHS / 256, 256, 0, stream>>>(gate_w, mapper_w, gateMapT);

    // bf16 staging copies (natural layouts, no transpose)
    {
        int n1 = kTE * kHS3 * kHS2;
        copybf_kernel<<<(n1 + 255) / 256, 256, 0, stream>>>(grue_wih, wihB, n1);
        int n2 = kHS * kHS2;
        copybf_kernel<<<(n2 + 255) / 256, 256, 0, stream>>>(fe_w, WnB, n2);  // Wn = fe_w[:512]
        copybf_kernel<<<(n2 + 255) / 256, 256, 0, stream>>>(
            fe_w + (size_t)(kHS + 1) * kHS2, WsB, n2);                        // Ws = fe_w[513:]
        // Wh block of COMB: rows 3072.. = whh[t] natural (1536x512)
        int n3 = kHS3 * kHS;
        for (int t = 0; t < kTE; ++t)
            copybf_kernel<<<(n3 + 255) / 256, 256, 0, stream>>>(
                grue_whh + (size_t)t * n3,
                COMB + ((size_t)t * kNC + 2 * kHS3) * kHS, n3);
    }
    // COMB_U[t] = wih[t] @ Wn^T  (1536x512), COMB_V[t] = wih[t] @ Ws^T
    for (int t = 0; t < kTE; ++t) {
        const ushort* At = wihB + (size_t)t * kHS3 * kHS2;
        launch_gemm<ushort>(At, kHS2, WnB,
                            COMB + (size_t)t * kNC * kHS, nullptr,
                            kHS3, kHS, kHS2, stream);
        launch_gemm<ushort>(At, kHS2, WsB,
                            COMB + ((size_t)t * kNC + kHS3) * kHS, nullptr,
                            kHS3, kHS, kHS2, stream);
    }

    for (int b0 = 0; b0 < kB; b0 += CH) {
        const int MC = CH * kN;  // rows (multiple of 128)
        ushort* P  = (ushort*)chunkBase;                 // MC x 4608 bf16
        ushort* AP = P  + (size_t)MC * kNC;              // MC x 1536 bf16
        ushort* H  = AP + (size_t)MC * kHS3;             // MC x 512  bf16
        float*  G12 = (float*)P;                         // MC x 2048 f32 (overlay)

        hinit_kernel<<<MC * kHS / 256, 256, 0, stream>>>(
            node_types + (size_t)b0 * kN, finit_w, finit_b, H);

        for (int t = 0; t < kTE; ++t) {
            // P = H @ COMB[t]^T   (MC x 4608, K=512)
            launch_gemm<ushort>(H, kHS, COMB + (size_t)t * kNC * kHS, P,
                                nullptr, MC, kNC, kHS, stream);
            // AP = adj^T P_U      (MC x 1536)
            {
                dim3 g(kHS3 / 256, CH);
                mixer_kernel<<<g, 256, 0, stream>>>(
                    adj + (size_t)b0 * kN * kN, P, AP);
            }
            // full GRU gating (H in place)
            gate_kernel<<<MC * kHS / 256, 256, 0, stream>>>(
                H, AP, P, deg + (size_t)b0 * kN, bewih + (size_t)t * kHS3,
                grue_bih + (size_t)t * kHS3, grue_bhh + (size_t)t * kHS3, hp);
        }

        // readout: G12 = H @ [gate|mapper]^T + [gate_b|0]  (MC x 2048, f32)
        launch_gemm<float>(H, kHS, gateMapT, G12, biasRO, MC, 2048, kHS, stream);
        hg_kernel<<<CH * kGS / 256, 256, 0, stream>>>(G12, Hg);
        fc_kernel<<<CH, 64, 0, stream>>>(Hg, fc1_w, fc1_b, fc2_w, fc2_b, out, b0);
    }
}